// Round 5
// baseline (860.544 us; speedup 1.0000x reference)
//
#include <hip/hip_runtime.h>
#include <hip/hip_bf16.h>

// LSTM: T=2048, B=512, INPUT=42, HIDDEN=64. Output uses ONLY batch element 511.
// Single-row recurrence: 2048 sequential steps of a 256x64 matvec +
// activations on ONE block (4 waves, 1 CU). Latency-chain-bound.
//
// History: R6 quad DPP + pk_fma -> 846us; R7 exp2-prescale -> 758.6
// (scan 541); R8 distributed per-gate acts -> 722.5 (scan 505); R9 XOR-slot
// select-free reduce (matched -36us); R10 tail squeeze -> NEUTRAL (only
// ~8 cyc was on-path => step is a rigid serial skeleton; biggest items are
// the post-barrier LDS read-wait (~120cyc) and write-drain).
// R11 (this): overlap the exchange toll.
//  (1) FULL-K rows: lane (kc,u) = gate kc of unit u over ALL 64 k. No
//      cross-lane reduce at all (DPP reduce deleted); h read as uniform
//      broadcast b128s; 8-acc pk_add merge tree.
//  (2) EARLY OWN-CHUNK READ: own wave produces exactly h[16w..16w+16), so
//      after write + lgkmcnt(0) (own-wave order), read the own chunk BEFORE
//      a RAW s_barrier (no waitcnt) -> its ~120cyc latency overlaps the
//      barrier. Post-barrier FMAs start on the own chunk while the 12
//      cross-chunk reads fly. Weights chunk-rotated at load so FMA indices
//      stay compile-time (no scratch).

#define T_STEPS 2048
#define BATCH   512
#define NIN     42
#define NH      64
#define NG      256   // 4*NH
#define CH      16    // scan steps per chunk
#define NCHUNK  (T_STEPS / CH)
#define XT      16    // timesteps per xproj block

#define LOG2E  1.44269504f
#define TWOL2E 2.88539008f

#if __has_builtin(__builtin_amdgcn_exp2f)
#define EXP2F __builtin_amdgcn_exp2f
#else
#define EXP2F exp2f
#endif

typedef float v2f __attribute__((ext_vector_type(2)));

// ---------------- Kernel 1: input projection for batch row 511 ----------------
// Output pre-scaled by log2(e) AND the destination gate's exp2 multiplier
// (+2 for tanh gate g, -1 for sigmoid gates i,f,o): seeds are exp2-ready.
__global__ __launch_bounds__(256) void xproj_kernel(
    const float* __restrict__ x, const float* __restrict__ W_ih,
    const float* __restrict__ b_ih, const float* __restrict__ b_hh,
    float* __restrict__ xp)
{
    const int g  = threadIdx.x;          // gate row 0..255
    const int t0 = blockIdx.x * XT;
    __shared__ float ws[NG * NIN];       // W_ih rows, packed [g][42]
    __shared__ float xs[XT][NIN];
    for (int i = threadIdx.x; i < NG * NIN; i += 256) ws[i] = W_ih[i];
    for (int i = threadIdx.x; i < XT * NIN; i += 256) {
        int tt = i / NIN, j = i % NIN;
        xs[tt][j] = x[((size_t)(t0 + tt) * BATCH + (BATCH - 1)) * NIN + j];
    }
    const float bias = b_ih[g] + b_hh[g];
    const float sc = ((g >> 6) == 2) ? (2.f * LOG2E) : (-LOG2E);
    __syncthreads();
    const float* wr = &ws[g * NIN];
    for (int tt = 0; tt < XT; ++tt) {
        float s = bias;
#pragma unroll
        for (int i = 0; i < NIN; ++i) s += wr[i] * xs[tt][i];
        xp[(size_t)(t0 + tt) * NG + g] = s * sc;
    }
}

// ---------------- Kernel 2: sequential LSTM scan (1 block, 256 threads) -------
__device__ __forceinline__ void pin2(v2f& v) {
    asm volatile("" : "+v"(v));
}

// quad_perm DPP mov (pure VALU).
// xor1: [1,0,3,2]=0xB1 ; xor2: [2,3,0,1]=0x4E ; xor3: [3,2,1,0]=0x1B
template <int CTRL>
__device__ __forceinline__ float dpp_mov(float v) {
    return __int_as_float(
        __builtin_amdgcn_mov_dpp(__float_as_int(v), CTRL, 0xF, 0xF, true));
}

__device__ __forceinline__ v2f fma2(v2f a, v2f b, v2f c) {
    return __builtin_elementwise_fma(a, b, c);   // -> v_pk_fma_f32
}

__global__ void
__attribute__((amdgpu_flat_work_group_size(256, 256), amdgpu_waves_per_eu(1, 1)))
lstm_scan_kernel(
    const float* __restrict__ W_hh, const float* __restrict__ xp,
    float* __restrict__ hout)
{
    const int lane = threadIdx.x;       // 0..255
    const int kc   = lane & 3;          // quad position == owned gate
    const int u    = lane >> 2;         // hidden unit
    const int wv   = lane >> 6;         // wave id 0..3 (uniform per wave)

    __shared__ __align__(16) float hbuf[2][NH];        // h exchange (double buf)
    if (lane < 2 * NH) ((float*)hbuf)[lane] = 0.f;

    // Own-gate activation constants (sums arrive exp2-pre-scaled):
    //   i (kc=0): v = 2l2e*sigmoid ; f,o: v = sigmoid ; g (kc=2): v = tanh
    const bool istanh = (kc == 2);
    const float gA = istanh ? -2.f : ((kc == 0) ? TWOL2E : 1.f);
    const float gB = istanh ? 1.f : 0.f;
    const float sc = istanh ? (2.f * LOG2E) : (-LOG2E);

    // Full-k weights for own gate row, chunk-rotated: FMA block m uses
    // h-chunk ((wv+m)&3); wr[m*8+j] covers k = ((wv+m)&3)*16 + 2j,+1.
    v2f wr[32];
    {
        const v2f* W = (const v2f*)(W_hh + ((size_t)kc * NH + u) * NH);
#pragma unroll
        for (int m = 0; m < 4; ++m) {
            const int c = (wv + m) & 3;
#pragma unroll
            for (int j = 0; j < 8; ++j) {
                v2f t = W[c * 8 + j];
                t.x *= sc; t.y *= sc;
                wr[m * 8 + j] = t;
            }
        }
#pragma unroll
        for (int j = 0; j < 32; ++j) pin2(wr[j]);
    }

    float C = 0.f;                      // cell state pre-scaled by 2*log2e
    const int seed_off = kc * NH + u;   // my xp column (gate kc, unit u)
    float* __restrict__ hp = hout + u;  // my output column (kc==0 lanes only)

    float xq[CH];
#pragma unroll
    for (int tt = 0; tt < CH; ++tt) xq[tt] = xp[tt * NG + seed_off];

    // chunk base offsets in float4 units
    const int coo = wv * 4;
    const int co1 = ((wv + 1) & 3) * 4;
    const int co2 = ((wv + 2) & 3) * 4;
    const int co3 = ((wv + 3) & 3) * 4;

    // ---- prologue: init is written by wave 0 only -> barrier FIRST, then
    // read the own chunk of buf0 (zeros).
    asm volatile("s_waitcnt lgkmcnt(0)" ::: "memory");
    __builtin_amdgcn_s_barrier();
    float4 o0, o1, o2, o3;
    {
        const float4* hb = (const float4*)hbuf[0] + coo;
        o0 = hb[0]; o1 = hb[1]; o2 = hb[2]; o3 = hb[3];
    }

    for (int ch = 0; ch < NCHUNK; ++ch) {
        float xn[CH];
        if (ch + 1 < NCHUNK) {
#pragma unroll
            for (int tt = 0; tt < CH; ++tt)
                xn[tt] = xp[(size_t)(ch + 1) * (CH * NG) + tt * NG + seed_off];
        }

#pragma unroll
        for (int tt = 0; tt < CH; ++tt) {
            const int p = tt & 1;
            const float4* hb = (const float4*)hbuf[p];
            // cross-chunk loads: issued first, per-use lgkm waits by compiler;
            // latency hides under the own-chunk FMA block below.
            float4 x10 = hb[co1 + 0], x11 = hb[co1 + 1],
                   x12 = hb[co1 + 2], x13 = hb[co1 + 3];
            float4 x20 = hb[co2 + 0], x21 = hb[co2 + 1],
                   x22 = hb[co2 + 2], x23 = hb[co2 + 3];
            float4 x30 = hb[co3 + 0], x31 = hb[co3 + 1],
                   x32 = hb[co3 + 2], x33 = hb[co3 + 3];

            v2f a0 = {xq[tt], 0.f}, a1 = {0.f, 0.f}, a2 = {0.f, 0.f},
                a3 = {0.f, 0.f}, a4 = {0.f, 0.f}, a5 = {0.f, 0.f},
                a6 = {0.f, 0.f}, a7 = {0.f, 0.f};
#define FQ(F0, F1, F2, F3, B)                                                   \
    a0 = fma2(wr[B + 0], (v2f){F0.x, F0.y}, a0);                                \
    a1 = fma2(wr[B + 1], (v2f){F0.z, F0.w}, a1);                                \
    a2 = fma2(wr[B + 2], (v2f){F1.x, F1.y}, a2);                                \
    a3 = fma2(wr[B + 3], (v2f){F1.z, F1.w}, a3);                                \
    a4 = fma2(wr[B + 4], (v2f){F2.x, F2.y}, a4);                                \
    a5 = fma2(wr[B + 5], (v2f){F2.z, F2.w}, a5);                                \
    a6 = fma2(wr[B + 6], (v2f){F3.x, F3.y}, a6);                                \
    a7 = fma2(wr[B + 7], (v2f){F3.z, F3.w}, a7);
            FQ(o0, o1, o2, o3, 0)          // own chunk: data already in regs
            FQ(x10, x11, x12, x13, 8)
            FQ(x20, x21, x22, x23, 16)
            FQ(x30, x31, x32, x33, 24)
#undef FQ
            // in-lane merge tree (pk adds), then horizontal
            v2f t0 = a0 + a1, t1 = a2 + a3, t2v = a4 + a5, t3 = a6 + a7;
            v2f u0v = t0 + t1, u1v = t2v + t3;
            v2f z = u0v + u1v;
            float s = z.x + z.y;

            // own-gate activation
            float e = EXP2F(s);
            float r = __builtin_amdgcn_rcpf(1.f + e);
            float v = __builtin_fmaf(gA, r, gB);   // lane0:2l2e*i 1:f 2:g 3:o

            // gather to lane kc==0 (3 parallel DPP movs)
            float w  = dpp_mov<0xB1>(v);   // lane0: f
            float g0 = dpp_mov<0x4E>(v);   // lane0: g
            float oo = dpp_mov<0x1B>(v);   // lane0: o

            float t2  = v * g0;            // 2l2e*(i*g)
            float p2o = -2.f * oo;
            C = __builtin_fmaf(w, C, t2);  // C = f*C + 2l2e*(i*g)
            float e2 = EXP2F(C);
            float rr = __builtin_amdgcn_rcpf(1.f + e2);
            float hn = __builtin_fmaf(p2o, rr, oo);  // o*tanh(c)

            if (kc == 0) {
                hbuf[1 - p][u] = hn;
                // fire-and-forget global store (vmcnt never drained in-loop)
                hp[(size_t)(ch * CH + tt) * NH] = hn;
            }
            // Drain MY wave's write only; early-read the OWN chunk of the
            // next buffer (produced entirely by my own wave -> no barrier
            // needed for it); then RAW barrier with the reads in flight.
            asm volatile("s_waitcnt lgkmcnt(0)" ::: "memory");
            __builtin_amdgcn_sched_barrier(0);
            {
                const float4* hbn = (const float4*)hbuf[1 - p] + coo;
                o0 = hbn[0]; o1 = hbn[1]; o2 = hbn[2]; o3 = hbn[3];
            }
            __builtin_amdgcn_sched_barrier(0);
            __builtin_amdgcn_s_barrier();
        }

#pragma unroll
        for (int tt = 0; tt < CH; ++tt) xq[tt] = xn[tt];
    }
}

// ---------------- Kernel 3: output projection out[t] = W_out @ h_t + b_out ----
__global__ __launch_bounds__(256) void outproj_kernel(
    const float* __restrict__ hout, const float* __restrict__ W_out,
    const float* __restrict__ b_out, float* __restrict__ out)
{
    int idx = blockIdx.x * blockDim.x + threadIdx.x;   // T*2
    if (idx >= T_STEPS * 2) return;
    int t = idx >> 1, o = idx & 1;
    const float* hr = hout + (size_t)t * NH;
    const float* wr = W_out + o * NH;
    float s = b_out[o];
#pragma unroll
    for (int j = 0; j < NH; ++j) s += hr[j] * wr[j];
    out[t * 2 + o] = s;
}

extern "C" void kernel_launch(void* const* d_in, const int* in_sizes, int n_in,
                              void* d_out, int out_size, void* d_ws, size_t ws_size,
                              hipStream_t stream) {
    const float* x     = (const float*)d_in[0];
    const float* W_ih  = (const float*)d_in[1];
    const float* W_hh  = (const float*)d_in[2];
    const float* b_ih  = (const float*)d_in[3];
    const float* b_hh  = (const float*)d_in[4];
    const float* W_out = (const float*)d_in[5];
    const float* b_out = (const float*)d_in[6];
    float* out = (float*)d_out;

    // workspace layout: xp (T*256 floats) | hout (T*64 floats)  = 2.5 MB
    float* xp   = (float*)d_ws;
    float* hout = xp + (size_t)T_STEPS * NG;

    xproj_kernel<<<T_STEPS / XT, 256, 0, stream>>>(x, W_ih, b_ih, b_hh, xp);
    lstm_scan_kernel<<<1, 256, 0, stream>>>(W_hh, xp, hout);
    outproj_kernel<<<(T_STEPS * 2 + 255) / 256, 256, 0, stream>>>(hout, W_out, b_out, out);
}

// Round 6
// 722.441 us; speedup vs baseline: 1.1912x; 1.1912x over previous
//
#include <hip/hip_runtime.h>
#include <hip/hip_bf16.h>

// LSTM: T=2048, B=512, INPUT=42, HIDDEN=64. Output uses ONLY batch element 511
// (reference indexes lstm_out[:, -1, :]). Single-row recurrence: 2048
// sequential steps of a 256x64 matvec + activations on ONE block.
//
// History: R5 waves_per_eu(1,1) residency; R6 quad DPP + pk_fma -> 846us;
// R7 exp2-prescale + direct global h store -> 758.6 (scan 541); R8 distributed
// per-gate activations (trans 10->4/step) -> 722.5 (scan 505); R9 XOR-slot
// select-free reduce (matched, -36us); R10 tail squeeze (0x1B gather, gm into
// xproj, CH=16) -> neutral 505.3; R11 full-k rows + pre-barrier own-chunk read
// -> REGRESSED 649.6 (LDS read instrs 4->16/step: ~12cyc/instr pipe
// serialization exceeded the 120cyc latency it hid; VALUBusy 0.151->0.121
// while time rose).
// R12 (this): REVERT to the proven R10 structure (505.3us scan / 722.5us
// total). Step model (confirmed by 3 matched + 2 refuted predictions):
// read-wait ~130 + FMA 64 + reduce 25 + act 40 + gather 10 + C-tail 60 +
// write/drain 50 + barrier 40 ~= 590cyc measured; VALUBusy 39% of the single
// active CU at 2.4GHz matches the instruction count. Latency-floor candidate.

#define T_STEPS 2048
#define BATCH   512
#define NIN     42
#define NH      64
#define NG      256   // 4*NH
#define CH      16    // scan steps per chunk
#define NCHUNK  (T_STEPS / CH)
#define XT      16    // timesteps per xproj block

#define LOG2E  1.44269504f
#define TWOL2E 2.88539008f

#if __has_builtin(__builtin_amdgcn_exp2f)
#define EXP2F __builtin_amdgcn_exp2f
#else
#define EXP2F exp2f
#endif

typedef float v2f __attribute__((ext_vector_type(2)));

// ---------------- Kernel 1: input projection for batch row 511 ----------------
// Output pre-scaled by log2(e) AND the destination gate's exp2 multiplier gm
// (gm = +2 for the tanh gate g, -1 for sigmoid gates i,f,o), so the scan's
// seeds are exp2-ready with zero scan-side multiplies.
__global__ __launch_bounds__(256) void xproj_kernel(
    const float* __restrict__ x, const float* __restrict__ W_ih,
    const float* __restrict__ b_ih, const float* __restrict__ b_hh,
    float* __restrict__ xp)
{
    const int g  = threadIdx.x;          // gate row 0..255
    const int t0 = blockIdx.x * XT;
    __shared__ float ws[NG * NIN];       // W_ih rows, packed [g][42]
    __shared__ float xs[XT][NIN];
    for (int i = threadIdx.x; i < NG * NIN; i += 256) ws[i] = W_ih[i];
    for (int i = threadIdx.x; i < XT * NIN; i += 256) {
        int tt = i / NIN, j = i % NIN;
        xs[tt][j] = x[((size_t)(t0 + tt) * BATCH + (BATCH - 1)) * NIN + j];
    }
    const float bias = b_ih[g] + b_hh[g];
    // gate index = g>>6 (PyTorch order i,f,g,o); gate 2 is tanh.
    const float sc = ((g >> 6) == 2) ? (2.f * LOG2E) : (-LOG2E);
    __syncthreads();
    const float* wr = &ws[g * NIN];
    for (int tt = 0; tt < XT; ++tt) {
        float s = bias;
#pragma unroll
        for (int i = 0; i < NIN; ++i) s += wr[i] * xs[tt][i];
        xp[(size_t)(t0 + tt) * NG + g] = s * sc;
    }
}

// ---------------- Kernel 2: sequential LSTM scan (1 block, 256 threads) -------
// Barrier draining ONLY LDS ops (lgkmcnt); global loads/stores stay in flight.
__device__ __forceinline__ void wg_barrier_lgkm() {
    asm volatile("s_waitcnt lgkmcnt(0)\n\ts_barrier" ::: "memory");
}

__device__ __forceinline__ void pin2(v2f& v) {
    asm volatile("" : "+v"(v));
}

// quad_perm DPP mov (pure VALU; no LDS pipe).
// xor1: [1,0,3,2]=0xB1 ; xor2: [2,3,0,1]=0x4E ; xor3: [3,2,1,0]=0x1B
template <int CTRL>
__device__ __forceinline__ float dpp_mov(float v) {
    return __int_as_float(
        __builtin_amdgcn_mov_dpp(__float_as_int(v), CTRL, 0xF, 0xF, true));
}

__device__ __forceinline__ v2f fma2(v2f a, v2f b, v2f c) {
    return __builtin_elementwise_fma(a, b, c);   // -> v_pk_fma_f32
}

__global__ void
__attribute__((amdgpu_flat_work_group_size(256, 256), amdgpu_waves_per_eu(1, 1)))
lstm_scan_kernel(
    const float* __restrict__ W_hh, const float* __restrict__ xp,
    float* __restrict__ hout)
{
    const int lane = threadIdx.x;       // 0..255
    const int kc   = lane & 3;          // quad position == owned gate == k-chunk
    const int u    = lane >> 2;         // hidden unit

    __shared__ __align__(16) float hbuf[2][NH];        // h exchange (double buf)
    if (lane < NH) { hbuf[0][lane] = 0.f; hbuf[1][lane] = 0.f; }

    // Per-lane activation constants for OWN gate kc (raw sums arrive already
    // scaled for exp2):
    //   i (kc=0): v = 2l2e * sigmoid = 2l2e*rcp(1+e)   -> gA=2l2e, gB=0
    //   f,o     : v = sigmoid = rcp(1+e)               -> gA=1,    gB=0
    //   g (kc=2): v = tanh = fma(-2, rcp(1+e), 1)      -> gA=-2,   gB=1
    const bool istanh = (kc == 2);
    const float gA = istanh ? -2.f : ((kc == 0) ? TWOL2E : 1.f);
    const float gB = istanh ? 1.f : 0.f;

    // XOR-slot permutation: slot r of lane kc accumulates gate (r^kc), k-chunk
    // kc. Weight scale absorbs log2e and the destination gate's gm.
    const int g0i = 0 ^ kc, g1i = 1 ^ kc, g2i = 2 ^ kc, g3i = 3 ^ kc;
    const float f0 = LOG2E * ((g0i == 2) ? 2.f : -1.f);
    const float f1 = LOG2E * ((g1i == 2) ? 2.f : -1.f);
    const float f2 = LOG2E * ((g2i == 2) ? 2.f : -1.f);
    const float f3 = LOG2E * ((g3i == 2) ? 2.f : -1.f);
    const v2f SC0 = {f0, f0}, SC1 = {f1, f1}, SC2 = {f2, f2}, SC3 = {f3, f3};

    const v2f* W0 = (const v2f*)(W_hh + ((size_t)g0i * NH + u) * NH + kc * 16);
    const v2f* W1 = (const v2f*)(W_hh + ((size_t)g1i * NH + u) * NH + kc * 16);
    const v2f* W2 = (const v2f*)(W_hh + ((size_t)g2i * NH + u) * NH + kc * 16);
    const v2f* W3 = (const v2f*)(W_hh + ((size_t)g3i * NH + u) * NH + kc * 16);
    v2f w0a=W0[0]*SC0, w0b=W0[1]*SC0, w0c=W0[2]*SC0, w0d=W0[3]*SC0,
        w0e=W0[4]*SC0, w0f=W0[5]*SC0, w0g=W0[6]*SC0, w0h=W0[7]*SC0;
    v2f w1a=W1[0]*SC1, w1b=W1[1]*SC1, w1c=W1[2]*SC1, w1d=W1[3]*SC1,
        w1e=W1[4]*SC1, w1f=W1[5]*SC1, w1g=W1[6]*SC1, w1h=W1[7]*SC1;
    v2f w2a=W2[0]*SC2, w2b=W2[1]*SC2, w2c=W2[2]*SC2, w2d=W2[3]*SC2,
        w2e=W2[4]*SC2, w2f=W2[5]*SC2, w2g=W2[6]*SC2, w2h=W2[7]*SC2;
    v2f w3a=W3[0]*SC3, w3b=W3[1]*SC3, w3c=W3[2]*SC3, w3d=W3[3]*SC3,
        w3e=W3[4]*SC3, w3f=W3[5]*SC3, w3g=W3[6]*SC3, w3h=W3[7]*SC3;
    pin2(w0a); pin2(w0b); pin2(w0c); pin2(w0d); pin2(w0e); pin2(w0f); pin2(w0g); pin2(w0h);
    pin2(w1a); pin2(w1b); pin2(w1c); pin2(w1d); pin2(w1e); pin2(w1f); pin2(w1g); pin2(w1h);
    pin2(w2a); pin2(w2b); pin2(w2c); pin2(w2d); pin2(w2e); pin2(w2f); pin2(w2g); pin2(w2h);
    pin2(w3a); pin2(w3b); pin2(w3c); pin2(w3d); pin2(w3e); pin2(w3f); pin2(w3g); pin2(w3h);

    float C = 0.f;                      // cell state pre-scaled by 2*log2e
    const int seed_off = kc * NH + u;   // my xp column (gate kc, unit u)
    float* __restrict__ hp = hout + u;  // my output column (kc==0 lanes only)

    // Seeds arrive fully pre-scaled from xproj (log2e * own-gate gm).
    float xq[CH];
#pragma unroll
    for (int tt = 0; tt < CH; ++tt) xq[tt] = xp[tt * NG + seed_off];

    wg_barrier_lgkm();                  // hbuf zeros visible

    for (int ch = 0; ch < NCHUNK; ++ch) {
        float xn[CH];
        if (ch + 1 < NCHUNK) {
#pragma unroll
            for (int tt = 0; tt < CH; ++tt)
                xn[tt] = xp[(size_t)(ch + 1) * (CH * NG) + tt * NG + seed_off];
        }

#pragma unroll
        for (int tt = 0; tt < CH; ++tt) {
            const int p = tt & 1;
            const float4* hb = (const float4*)hbuf[p];
            float4 hv0 = hb[kc * 4 + 0];
            float4 hv1 = hb[kc * 4 + 1];
            float4 hv2 = hb[kc * 4 + 2];
            float4 hv3 = hb[kc * 4 + 3];
            v2f h0 = {hv0.x, hv0.y}, h1 = {hv0.z, hv0.w};
            v2f h2 = {hv1.x, hv1.y}, h3 = {hv1.z, hv1.w};
            v2f h4 = {hv2.x, hv2.y}, h5 = {hv2.z, hv2.w};
            v2f h6 = {hv3.x, hv3.y}, h7 = {hv3.z, hv3.w};

            // Seed lands in slot 0 only: slot 0 of lane kc routes gate kc,
            // counted exactly once across the quad.
            v2f a0 = {xq[tt], 0.f};
            v2f a1 = {0.f, 0.f}, a2 = {0.f, 0.f}, a3 = {0.f, 0.f};

            a0 = fma2(w0a, h0, a0); a0 = fma2(w0b, h1, a0);
            a0 = fma2(w0c, h2, a0); a0 = fma2(w0d, h3, a0);
            a0 = fma2(w0e, h4, a0); a0 = fma2(w0f, h5, a0);
            a0 = fma2(w0g, h6, a0); a0 = fma2(w0h, h7, a0);
            a1 = fma2(w1a, h0, a1); a1 = fma2(w1b, h1, a1);
            a1 = fma2(w1c, h2, a1); a1 = fma2(w1d, h3, a1);
            a1 = fma2(w1e, h4, a1); a1 = fma2(w1f, h5, a1);
            a1 = fma2(w1g, h6, a1); a1 = fma2(w1h, h7, a1);
            a2 = fma2(w2a, h0, a2); a2 = fma2(w2b, h1, a2);
            a2 = fma2(w2c, h2, a2); a2 = fma2(w2d, h3, a2);
            a2 = fma2(w2e, h4, a2); a2 = fma2(w2f, h5, a2);
            a2 = fma2(w2g, h6, a2); a2 = fma2(w2h, h7, a2);
            a3 = fma2(w3a, h0, a3); a3 = fma2(w3b, h1, a3);
            a3 = fma2(w3c, h2, a3); a3 = fma2(w3d, h3, a3);
            a3 = fma2(w3e, h4, a3); a3 = fma2(w3f, h5, a3);
            a3 = fma2(w3g, h6, a3); a3 = fma2(w3h, h7, a3);

            float p0 = a0.x + a0.y;
            float p1 = a1.x + a1.y;
            float p2 = a2.x + a2.y;
            float p3 = a3.x + a3.y;

            // Uniform transpose-reduce (no selects): lane j ends with the
            // FULL pre-scaled sum of gate j.
            float r0 = p0 + dpp_mov<0xB1>(p1);
            float r1 = p2 + dpp_mov<0xB1>(p3);
            float s  = r0 + dpp_mov<0x4E>(r1);

            // Own-gate activation; lane0 directly produces 2l2e*i.
            float e = EXP2F(s);
            float r = __builtin_amdgcn_rcpf(1.f + e);
            float v = __builtin_fmaf(gA, r, gB);   // lane0:2l2e*i 1:f 2:g 3:o

            // Gather to lane kc==0 — all three depend only on v (parallel).
            float w  = dpp_mov<0xB1>(v);   // lane0: f
            float g0 = dpp_mov<0x4E>(v);   // lane0: g
            float oo = dpp_mov<0x1B>(v);   // lane0: o

            float t2  = v * g0;            // 2l2e*(i*g)  (lane0)
            float p2o = -2.f * oo;         // off-path for the tail fma
            C = __builtin_fmaf(w, C, t2);  // C = f*C + 2l2e*(i*g)
            float e2 = EXP2F(C);           // = e^(2c)
            float rr = __builtin_amdgcn_rcpf(1.f + e2);
            float hn = __builtin_fmaf(p2o, rr, oo);  // o*tanh(c)

            if (kc == 0) {
                hbuf[1 - p][u] = hn;
                // fire-and-forget global store; vmcnt is NOT drained by the
                // lgkm-only barrier, so this never sits on the critical path.
                hp[(size_t)(ch * CH + tt) * NH] = hn;
            }
            wg_barrier_lgkm();
        }

#pragma unroll
        for (int tt = 0; tt < CH; ++tt) xq[tt] = xn[tt];
    }
}

// ---------------- Kernel 3: output projection out[t] = W_out @ h_t + b_out ----
__global__ __launch_bounds__(256) void outproj_kernel(
    const float* __restrict__ hout, const float* __restrict__ W_out,
    const float* __restrict__ b_out, float* __restrict__ out)
{
    int idx = blockIdx.x * blockDim.x + threadIdx.x;   // T*2
    if (idx >= T_STEPS * 2) return;
    int t = idx >> 1, o = idx & 1;
    const float* hr = hout + (size_t)t * NH;
    const float* wr = W_out + o * NH;
    float s = b_out[o];
#pragma unroll
    for (int j = 0; j < NH; ++j) s += hr[j] * wr[j];
    out[t * 2 + o] = s;
}

extern "C" void kernel_launch(void* const* d_in, const int* in_sizes, int n_in,
                              void* d_out, int out_size, void* d_ws, size_t ws_size,
                              hipStream_t stream) {
    const float* x     = (const float*)d_in[0];
    const float* W_ih  = (const float*)d_in[1];
    const float* W_hh  = (const float*)d_in[2];
    const float* b_ih  = (const float*)d_in[3];
    const float* b_hh  = (const float*)d_in[4];
    const float* W_out = (const float*)d_in[5];
    const float* b_out = (const float*)d_in[6];
    float* out = (float*)d_out;

    // workspace layout: xp (T*256 floats) | hout (T*64 floats)  = 2.5 MB
    float* xp   = (float*)d_ws;
    float* hout = xp + (size_t)T_STEPS * NG;

    xproj_kernel<<<T_STEPS / XT, 256, 0, stream>>>(x, W_ih, b_ih, b_hh, xp);
    lstm_scan_kernel<<<1, 256, 0, stream>>>(W_hh, xp, hout);
    outproj_kernel<<<(T_STEPS * 2 + 255) / 256, 256, 0, stream>>>(hout, W_out, b_out, out);
}